// Round 4
// baseline (419.817 us; speedup 1.0000x reference)
//
#include <hip/hip_runtime.h>
#include <stdint.h>

typedef __attribute__((ext_vector_type(8))) short short8;
typedef __attribute__((ext_vector_type(4))) float f32x4;
typedef __attribute__((ext_vector_type(4))) unsigned short u16x4;

#define DEVI static __device__ __forceinline__

DEVI unsigned short f2bf(float f) {
  unsigned int u = __builtin_bit_cast(unsigned int, f);
  u += 0x7fffu + ((u >> 16) & 1u);
  return (unsigned short)(u >> 16);
}

DEVI void glds16(const void* g, void* lds_uniform) {
  typedef const __attribute__((address_space(1))) unsigned int* gp_t;
  typedef __attribute__((address_space(3))) unsigned int* lp_t;
  __builtin_amdgcn_global_load_lds((gp_t)(uintptr_t)g, (lp_t)(uintptr_t)lds_uniform, 16, 0, 0);
}

// ---------------- conversions ----------------

__global__ __launch_bounds__(256) void cvt_x_kernel(const float* __restrict__ in,
                                                    unsigned short* __restrict__ out, int n4) {
  typedef __attribute__((ext_vector_type(4))) float f4;
  typedef __attribute__((ext_vector_type(4))) unsigned short u4;
  const f4* in4 = (const f4*)in;
  u4* out4 = (u4*)out;
  for (int i = blockIdx.x * blockDim.x + threadIdx.x; i < n4; i += gridDim.x * blockDim.x) {
    f4 v = in4[i];
    u4 o;
    o[0] = f2bf(v[0]); o[1] = f2bf(v[1]); o[2] = f2bf(v[2]); o[3] = f2bf(v[3]);
    out4[i] = o;
  }
}

// fused Wq/Wk/Wv transpose-convert: in fp32 [16][1024][64] x3 -> out bf16 [3][16][64][1024]
__global__ __launch_bounds__(256) void cvt_w3_kernel(const float* __restrict__ Wq,
                                                     const float* __restrict__ Wk,
                                                     const float* __restrict__ Wv,
                                                     unsigned short* __restrict__ out) {
  int i = blockIdx.x * blockDim.x + threadIdx.x;  // 3 * 2^20 total
  int z = i >> 20, loc = i & 1048575;
  const float* W = (z == 0) ? Wq : ((z == 1) ? Wk : Wv);
  int r = loc & 1023;
  int rest = loc >> 10;
  int c = rest & 63, hh = rest >> 6;
  out[i] = f2bf(W[((((size_t)hh << 10) | (size_t)r) << 6) | (size_t)c]);
}

// transpose-convert: in fp32 [R=1024][C=1024], out bf16 [C][R]
__global__ __launch_bounds__(256) void cvt_w_kernel(const float* __restrict__ in,
                                                    unsigned short* __restrict__ out,
                                                    int total, int log2C) {
  int i = blockIdx.x * blockDim.x + threadIdx.x;
  if (i >= total) return;
  int r = i & 1023;
  int rest = i >> 10;
  int c = rest & ((1 << log2C) - 1);
  int b = rest >> log2C;
  out[i] = f2bf(in[((((size_t)b << 10) | (size_t)r) << log2C) | (size_t)c]);
}

// ---------------- 256x256 8-phase GEMM: C = A[M x 1024] * Bt[N x 1024]^T ----------------
// 8 waves (2M x 4N), BK=64, dbuf LDS 128 KiB, counted vmcnt(8), raw barriers, setprio.
// MODE 0: N=3072 fused QKV; n<2048 -> bf16 scatter [bh][t][d]; n>=2048 -> V^T [bh][d][t] pack x4
// MODE 1: N=1024, out fp32 row-major [M][1024] + bias
template <int MODE>
__global__ __launch_bounds__(512, 2)
void gemm256(const unsigned short* __restrict__ A,
             const unsigned short* __restrict__ Bt,
             unsigned short* __restrict__ OutB,
             float* __restrict__ OutF,
             const float* __restrict__ bias) {
  __shared__ unsigned short As[2][256 * 64];  // [row][k], chunk-swizzled per row
  __shared__ unsigned short Bs[2][256 * 64];
  const int tid = threadIdx.x;
  const int w = tid >> 6, lane = tid & 63;
  const int l15 = lane & 15, l4 = lane >> 4;
  const int wm = w >> 2, wn = w & 3;  // 2 x 4 wave grid; wave owns 128 rows x 64 cols

  // XCD-bijective swizzle + linear n-fastest within XCD (exclusive A stripes per XCD)
  const int phys = blockIdx.x;
  const int wgid = (MODE == 0) ? ((phys & 7) * 96 + (phys >> 3))
                               : ((phys & 7) * 32 + (phys >> 3));
  const int sm = (MODE == 0) ? (wgid / 12) : (wgid >> 2);
  const int sn = (MODE == 0) ? (wgid % 12) : (wgid & 3);
  const int bm = sm << 8, bn = sn << 8;

  // staging geometry: issue j covers chunks C = j*512 + tid; row=C>>3, slot cc holds k-chunk cc^(row&7)
  int srow[4], skoff[4];
#pragma unroll
  for (int j = 0; j < 4; ++j) {
    int C = (j << 9) + tid;
    srow[j] = C >> 3;
    skoff[j] = (((C & 7) ^ (srow[j] & 7)) << 3);
  }

  f32x4 acc[8][4];
#pragma unroll
  for (int i = 0; i < 8; ++i)
#pragma unroll
    for (int j = 0; j < 4; ++j) acc[i][j] = f32x4{0.f, 0.f, 0.f, 0.f};

  auto stage = [&](int buf, int kt) {
    const int k0 = kt << 6;
#pragma unroll
    for (int j = 0; j < 4; ++j)
      glds16(A + (size_t)(bm + srow[j]) * 1024 + k0 + skoff[j],
             &As[buf][((j << 9) + (w << 6)) << 3]);
#pragma unroll
    for (int j = 0; j < 4; ++j)
      glds16(Bt + (size_t)(bn + srow[j]) * 1024 + k0 + skoff[j],
             &Bs[buf][((j << 9) + (w << 6)) << 3]);
  };

  // prologue: stage tiles 0 and 1; retire tile 0 (leave tile 1's 8 loads in flight)
  stage(0, 0);
  stage(1, 1);
  asm volatile("s_waitcnt vmcnt(8)" ::: "memory");
  __builtin_amdgcn_s_barrier();
  __builtin_amdgcn_sched_barrier(0);

  for (int kt = 0; kt < 16; ++kt) {
    const int cur = kt & 1;
    if (kt >= 1) {
      // buf[cur^1]'s last reader finished before tile (kt-1)'s final barrier -> safe to refill
      if (kt < 15) {
        stage(cur ^ 1, kt + 1);
        asm volatile("s_waitcnt vmcnt(8)" ::: "memory");  // tile kt's 8 loads retired; kt+1's in flight
      } else {
        asm volatile("s_waitcnt vmcnt(0)" ::: "memory");
      }
      __builtin_amdgcn_s_barrier();
      __builtin_amdgcn_sched_barrier(0);
    }
    // 4 quadrant phases: (qr,qc) m-half x n-half of this wave's 128x64 output
#pragma unroll
    for (int q = 0; q < 4; ++q) {
      const int qr = q >> 1, qc = q & 1;
      short8 af[4][2], bfr[2][2];
#pragma unroll
      for (int ri = 0; ri < 4; ++ri)
#pragma unroll
        for (int ks = 0; ks < 2; ++ks) {
          int row = (wm << 7) + (qr << 6) + (ri << 4) + l15;
          int ch = ((ks << 2) + l4) ^ (row & 7);
          af[ri][ks] = *(const short8*)&As[cur][(row << 6) + (ch << 3)];
        }
#pragma unroll
      for (int ni = 0; ni < 2; ++ni)
#pragma unroll
        for (int ks = 0; ks < 2; ++ks) {
          int row = (wn << 6) + (qc << 5) + (ni << 4) + l15;
          int ch = ((ks << 2) + l4) ^ (row & 7);
          bfr[ni][ks] = *(const short8*)&Bs[cur][(row << 6) + (ch << 3)];
        }
      __builtin_amdgcn_s_barrier();
      __builtin_amdgcn_s_setprio(1);
#pragma unroll
      for (int ks = 0; ks < 2; ++ks)
#pragma unroll
        for (int ri = 0; ri < 4; ++ri)
#pragma unroll
          for (int ni = 0; ni < 2; ++ni)
            acc[(qr << 2) + ri][(qc << 1) + ni] = __builtin_amdgcn_mfma_f32_16x16x32_bf16(
                af[ri][ks], bfr[ni][ks], acc[(qr << 2) + ri][(qc << 1) + ni], 0, 0, 0);
      __builtin_amdgcn_s_setprio(0);
      __builtin_amdgcn_s_barrier();
    }
  }

  // epilogue: m = bm + wm*128 + mi*16 + l4*4 + r ; n = bn + wn*64 + ni*16 + l15
  if (MODE == 0) {
    const int nb = bn + (wn << 6);
    const int z = nb >> 10;  // wave-uniform (bn mult of 256, 256 | 1024)
    if (z < 2) {
      unsigned short* Oz = OutB + (size_t)z * 16777216;
#pragma unroll
      for (int mi = 0; mi < 8; ++mi) {
#pragma unroll
        for (int r = 0; r < 4; ++r) {
          int m = bm + (wm << 7) + (mi << 4) + (l4 << 2) + r;
          int b = m >> 10, t = m & 1023;
#pragma unroll
          for (int ni = 0; ni < 4; ++ni) {
            int n1 = (nb + (ni << 4) + l15) & 1023;
            int h = n1 >> 6, d = n1 & 63;
            Oz[((size_t)(b * 16 + h) * 1024 + t) * 64 + d] = f2bf(acc[mi][ni][r]);
          }
        }
      }
    } else {
      // V^T: [bh][d][t], pack 4 consecutive t per lane
      unsigned short* Oz = OutB + (size_t)2 * 16777216;
#pragma unroll
      for (int mi = 0; mi < 8; ++mi) {
        int tb = bm + (wm << 7) + (mi << 4) + (l4 << 2);
        int bb = tb >> 10, tt = tb & 1023;
#pragma unroll
        for (int ni = 0; ni < 4; ++ni) {
          int n1 = (nb + (ni << 4) + l15) & 1023;
          int hh = n1 >> 6, dd = n1 & 63;
          u16x4 pk;
#pragma unroll
          for (int r = 0; r < 4; ++r) pk[r] = f2bf(acc[mi][ni][r]);
          *(u16x4*)&Oz[(((size_t)((bb << 4) + hh) << 6) + (size_t)dd) * 1024 + tt] = pk;
        }
      }
    }
  } else {
#pragma unroll
    for (int mi = 0; mi < 8; ++mi) {
#pragma unroll
      for (int r = 0; r < 4; ++r) {
        int m = bm + (wm << 7) + (mi << 4) + (l4 << 2) + r;
#pragma unroll
        for (int ni = 0; ni < 4; ++ni) {
          int n = bn + (wn << 6) + (ni << 4) + l15;
          OutF[(size_t)m * 1024 + n] = acc[mi][ni][r] + bias[n];
        }
      }
    }
  }
}

// ---------------- causal flash attention (swapped QK^T, single-barrier dbuf) ----------------
// 1-D grid 2048, XCD swizzle: each XCD owns 32 consecutive bh (K/V L2-resident per XCD).
// block bx handles q-tiles {15-bx, bx} (17 KV-iters uniform). wave w owns 16 q rows.
// K [bh][t][64]; V^T [bh][d][t]; swapped S^T = mfma(K, Q) so softmax is lane-local.
__global__ __launch_bounds__(256)
void attn_fa(const unsigned short* __restrict__ Qb,
             const unsigned short* __restrict__ Kb,
             const unsigned short* __restrict__ Vtb,
             unsigned short* __restrict__ Ob) {
  __shared__ unsigned short Ks[2][64 * 64];  // [kv][k=64], chunk-swizzled
  __shared__ unsigned short Vs[2][64 * 64];  // V^T [d][kv=64], chunk-swizzled
  __shared__ unsigned short Ps[4][16 * 64];  // per-wave P [qrow][kv], chunk-swizzled
  const int tid = threadIdx.x, w = tid >> 6, lane = tid & 63;
  const int l15 = lane & 15, l4 = lane >> 4;
  const int phys = blockIdx.x;
  const int ord = phys >> 3;
  const int bx = ord & 7;
  const int bh = ((phys & 7) << 5) | (ord >> 3);
  const unsigned short* Q = Qb + ((size_t)bh << 16);
  const unsigned short* K = Kb + ((size_t)bh << 16);
  const unsigned short* Vt = Vtb + ((size_t)bh << 16);
  const int b = bh >> 4, h = bh & 15;
  const float SC = 0.125f * 1.44269504088896340736f;  // 1/sqrt(64) * log2(e)
  const float NEGINF = -__builtin_inff();

  int srow[2], skoff[2];
#pragma unroll
  for (int c = 0; c < 2; ++c) {
    int C = (c << 8) + tid;
    int row = C >> 3, cc = C & 7;
    srow[c] = row;
    skoff[c] = ((cc ^ (row & 7)) << 3);
  }
  const int sdst = (w << 6) << 3;

  for (int ph = 0; ph < 2; ++ph) {
    const int qidx = ph ? bx : (15 - bx);
    const int q0 = qidx << 6;
    const int nt = qidx + 1;
    const int qrow = q0 + (w << 4) + l15;

    short8 bq0, bq1;
    {
      const unsigned short* qp = Q + (size_t)qrow * 64 + (l4 << 3);
      bq0 = *(const short8*)qp;
      bq1 = *(const short8*)(qp + 32);
    }

    f32x4 o[4];
#pragma unroll
    for (int nf = 0; nf < 4; ++nf) o[nf] = f32x4{0.f, 0.f, 0.f, 0.f};
    float mreg = NEGINF, lreg = 0.f;

#pragma unroll
    for (int c = 0; c < 2; ++c) {
      glds16(K + (size_t)(srow[c] << 6) + skoff[c], &Ks[0][(c << 11) + sdst]);
      glds16(Vt + (size_t)(srow[c] << 10) + skoff[c], &Vs[0][(c << 11) + sdst]);
    }
    __syncthreads();

    for (int it = 0; it < nt; ++it) {
      const int cur = it & 1;
      if (it + 1 < nt) {
        const int kv0n = (it + 1) << 6;
#pragma unroll
        for (int c = 0; c < 2; ++c) {
          glds16(K + (size_t)((kv0n + srow[c]) << 6) + skoff[c], &Ks[cur ^ 1][(c << 11) + sdst]);
          glds16(Vt + (size_t)(srow[c] << 10) + kv0n + skoff[c], &Vs[cur ^ 1][(c << 11) + sdst]);
        }
      }

      f32x4 s[4];
      __builtin_amdgcn_s_setprio(1);
#pragma unroll
      for (int n = 0; n < 4; ++n) {
        const int row = (n << 4) + l15;
        const int rb = row << 6;
        short8 ak0 = *(const short8*)&Ks[cur][rb + ((l4 ^ (row & 7)) << 3)];
        short8 ak1 = *(const short8*)&Ks[cur][rb + (((4 + l4) ^ (row & 7)) << 3)];
        f32x4 a = f32x4{0.f, 0.f, 0.f, 0.f};
        a = __builtin_amdgcn_mfma_f32_16x16x32_bf16(ak0, bq0, a, 0, 0, 0);
        a = __builtin_amdgcn_mfma_f32_16x16x32_bf16(ak1, bq1, a, 0, 0, 0);
        s[n] = a;
      }
      __builtin_amdgcn_s_setprio(0);

      const int kv0 = it << 6;
      const bool diag = (it == nt - 1);
      float p[4][4];
      float mx = NEGINF;
#pragma unroll
      for (int n = 0; n < 4; ++n)
#pragma unroll
        for (int r = 0; r < 4; ++r) {
          float v = s[n][r] * SC;
          if (diag) {
            int kvg = kv0 + (n << 4) + (l4 << 2) + r;
            v = (kvg <= qrow) ? v : NEGINF;
          }
          p[n][r] = v;
          mx = fmaxf(mx, v);
        }
      mx = fmaxf(mx, __shfl_xor(mx, 16));
      mx = fmaxf(mx, __shfl_xor(mx, 32));
      float mnew = fmaxf(mreg, mx);
      float alpha = exp2f(mreg - mnew);
      mreg = mnew;
      float rs = 0.f;
#pragma unroll
      for (int n = 0; n < 4; ++n)
#pragma unroll
        for (int r = 0; r < 4; ++r) {
          float pv = exp2f(p[n][r] - mreg);
          p[n][r] = pv;
          rs += pv;
        }
      rs += __shfl_xor(rs, 16);
      rs += __shfl_xor(rs, 32);
      lreg = lreg * alpha + rs;

      float a_r[4];
#pragma unroll
      for (int r = 0; r < 4; ++r)
        a_r[r] = __shfl(alpha, (lane & 0x30) | ((l4 << 2) | r));
#pragma unroll
      for (int nf = 0; nf < 4; ++nf)
#pragma unroll
        for (int r = 0; r < 4; ++r) o[nf][r] *= a_r[r];

#pragma unroll
      for (int n = 0; n < 4; ++n) {
        u16x4 pk;
#pragma unroll
        for (int r = 0; r < 4; ++r) pk[r] = f2bf(p[n][r]);
        const int kc = (n << 1) + (l4 >> 1);
        char* addr = (char*)&Ps[w][0] + (l15 << 7) + ((kc ^ (l15 & 7)) << 4) + ((l4 & 1) << 3);
        *(u16x4*)addr = pk;
      }

      short8 pa0 = *(const short8*)((char*)&Ps[w][0] + (l15 << 7) + ((l4 ^ (l15 & 7)) << 4));
      short8 pa1 = *(const short8*)((char*)&Ps[w][0] + (l15 << 7) + (((4 + l4) ^ (l15 & 7)) << 4));
      __builtin_amdgcn_s_setprio(1);
#pragma unroll
      for (int nf = 0; nf < 4; ++nf) {
        const int drow = (nf << 4) + l15;
        const int db = drow << 6;
        short8 vb0 = *(const short8*)&Vs[cur][db + ((l4 ^ (drow & 7)) << 3)];
        short8 vb1 = *(const short8*)&Vs[cur][db + (((4 + l4) ^ (drow & 7)) << 3)];
        o[nf] = __builtin_amdgcn_mfma_f32_16x16x32_bf16(pa0, vb0, o[nf], 0, 0, 0);
        o[nf] = __builtin_amdgcn_mfma_f32_16x16x32_bf16(pa1, vb1, o[nf], 0, 0, 0);
      }
      __builtin_amdgcn_s_setprio(0);
      __syncthreads();
    }

    float linv = 1.0f / lreg;
    float l_r[4];
#pragma unroll
    for (int r = 0; r < 4; ++r)
      l_r[r] = __shfl(linv, (lane & 0x30) | ((l4 << 2) | r));
#pragma unroll
    for (int r = 0; r < 4; ++r) {
      const int t = q0 + (w << 4) + (l4 << 2) + r;
      size_t base = ((size_t)(b * 1024 + t) << 10) + (h << 6);
#pragma unroll
      for (int nf = 0; nf < 4; ++nf)
        Ob[base + (nf << 4) + l15] = f2bf(o[nf][r] * l_r[r]);
    }
  }
}

// ---------------- launch ----------------

extern "C" void kernel_launch(void* const* d_in, const int* in_sizes, int n_in,
                              void* d_out, int out_size, void* d_ws, size_t ws_size,
                              hipStream_t stream) {
  const float* x  = (const float*)d_in[0];
  const float* Wq = (const float*)d_in[1];
  const float* Wk = (const float*)d_in[2];
  const float* Wv = (const float*)d_in[3];
  const float* Wo = (const float*)d_in[4];
  const float* bo = (const float*)d_in[5];
  float* out = (float*)d_out;

  unsigned char* ws = (unsigned char*)d_ws;
  unsigned short* xb  = (unsigned short*)(ws);                          // 32 MB (aliased by O later)
  unsigned short* wT  = (unsigned short*)(ws + 33554432);               // 3 x 2 MB (WqT,WkT,WvT contiguous)
  unsigned short* woT = (unsigned short*)(ws + 33554432 + 6291456);     // 2 MB
  unsigned short* qkv = (unsigned short*)(ws + 41943040);               // q,k [bh][t][d]; v^T [bh][d][t]
  unsigned short* Ob  = xb;  // x bf16 is dead after projections

  cvt_x_kernel<<<2048, 256, 0, stream>>>(x, xb, 4194304);
  cvt_w3_kernel<<<12288, 256, 0, stream>>>(Wq, Wk, Wv, wT);
  cvt_w_kernel<<<4096, 256, 0, stream>>>(Wo, woT, 1 << 20, 10);

  gemm256<0><<<768, 512, 0, stream>>>(xb, wT, qkv, nullptr, nullptr);
  attn_fa<<<2048, 256, 0, stream>>>(qkv, qkv + 16777216, qkv + 33554432, Ob);
  gemm256<1><<<256, 512, 0, stream>>>(Ob, woT, nullptr, out, bo);
}

// Round 5
// 389.580 us; speedup vs baseline: 1.0776x; 1.0776x over previous
//
#include <hip/hip_runtime.h>
#include <stdint.h>

typedef __attribute__((ext_vector_type(8))) short short8;
typedef __attribute__((ext_vector_type(4))) float f32x4;
typedef __attribute__((ext_vector_type(4))) unsigned short u16x4;

#define DEVI static __device__ __forceinline__

DEVI unsigned short f2bf(float f) {
  unsigned int u = __builtin_bit_cast(unsigned int, f);
  u += 0x7fffu + ((u >> 16) & 1u);
  return (unsigned short)(u >> 16);
}

DEVI void glds16(const void* g, void* lds_uniform) {
  typedef const __attribute__((address_space(1))) unsigned int* gp_t;
  typedef __attribute__((address_space(3))) unsigned int* lp_t;
  __builtin_amdgcn_global_load_lds((gp_t)(uintptr_t)g, (lp_t)(uintptr_t)lds_uniform, 16, 0, 0);
}

// ---------------- conversions ----------------

__global__ __launch_bounds__(256) void cvt_x_kernel(const float* __restrict__ in,
                                                    unsigned short* __restrict__ out, int n4) {
  typedef __attribute__((ext_vector_type(4))) float f4;
  typedef __attribute__((ext_vector_type(4))) unsigned short u4;
  const f4* in4 = (const f4*)in;
  u4* out4 = (u4*)out;
  for (int i = blockIdx.x * blockDim.x + threadIdx.x; i < n4; i += gridDim.x * blockDim.x) {
    f4 v = in4[i];
    u4 o;
    o[0] = f2bf(v[0]); o[1] = f2bf(v[1]); o[2] = f2bf(v[2]); o[3] = f2bf(v[3]);
    out4[i] = o;
  }
}

// fused Wq/Wk/Wv transpose-convert: in fp32 [16][1024][64] x3 -> out bf16 [3][16][64][1024]
__global__ __launch_bounds__(256) void cvt_w3_kernel(const float* __restrict__ Wq,
                                                     const float* __restrict__ Wk,
                                                     const float* __restrict__ Wv,
                                                     unsigned short* __restrict__ out) {
  int i = blockIdx.x * blockDim.x + threadIdx.x;  // 3 * 2^20 total
  int z = i >> 20, loc = i & 1048575;
  const float* W = (z == 0) ? Wq : ((z == 1) ? Wk : Wv);
  int r = loc & 1023;
  int rest = loc >> 10;
  int c = rest & 63, hh = rest >> 6;
  out[i] = f2bf(W[((((size_t)hh << 10) | (size_t)r) << 6) | (size_t)c]);
}

// transpose-convert: in fp32 [R=1024][C=1024], out bf16 [C][R]
__global__ __launch_bounds__(256) void cvt_w_kernel(const float* __restrict__ in,
                                                    unsigned short* __restrict__ out,
                                                    int total, int log2C) {
  int i = blockIdx.x * blockDim.x + threadIdx.x;
  if (i >= total) return;
  int r = i & 1023;
  int rest = i >> 10;
  int c = rest & ((1 << log2C) - 1);
  int b = rest >> log2C;
  out[i] = f2bf(in[((((size_t)b << 10) | (size_t)r) << log2C) | (size_t)c]);
}

// ---------------- 256x256 GEMM: C = A[M x 1024] * Bt[N x 1024]^T ----------------
// 8 waves (2M x 4N), BK=64, dbuf LDS 128 KiB.
// ONE barrier + ONE vmcnt(0) per K-tile; stage for kt+1 issued AFTER the barrier
// (race-free: all reads of buf^1 are consumed by pre-barrier MFMAs). No in-tile
// barriers: within a tile all waves only READ buf[cur], so the compiler is free
// to interleave ds_reads under MFMAs. A-fragments hoisted per m-half (read once).
// MODE 0: N=3072 fused QKV; n<2048 -> bf16 scatter [bh][t][d]; n>=2048 -> V^T [bh][d][t] pack x4
// MODE 1: N=1024, out fp32 row-major [M][1024] + bias
template <int MODE>
__global__ __launch_bounds__(512, 2)
void gemm256(const unsigned short* __restrict__ A,
             const unsigned short* __restrict__ Bt,
             unsigned short* __restrict__ OutB,
             float* __restrict__ OutF,
             const float* __restrict__ bias) {
  __shared__ unsigned short As[2][256 * 64];  // [row][k], chunk-swizzled per row
  __shared__ unsigned short Bs[2][256 * 64];
  const int tid = threadIdx.x;
  const int w = tid >> 6, lane = tid & 63;
  const int l15 = lane & 15, l4 = lane >> 4;
  const int wm = w >> 2, wn = w & 3;  // 2 x 4 wave grid; wave owns 128 rows x 64 cols

  // XCD-bijective swizzle + linear n-fastest within XCD (exclusive A stripes per XCD)
  const int phys = blockIdx.x;
  const int wgid = (MODE == 0) ? ((phys & 7) * 96 + (phys >> 3))
                               : ((phys & 7) * 32 + (phys >> 3));
  const int sm = (MODE == 0) ? (wgid / 12) : (wgid >> 2);
  const int sn = (MODE == 0) ? (wgid % 12) : (wgid & 3);
  const int bm = sm << 8, bn = sn << 8;

  // staging geometry: issue j covers chunks C = j*512 + tid; row=C>>3, slot cc holds k-chunk cc^(row&7)
  int srow[4], skoff[4];
#pragma unroll
  for (int j = 0; j < 4; ++j) {
    int C = (j << 9) + tid;
    srow[j] = C >> 3;
    skoff[j] = (((C & 7) ^ (srow[j] & 7)) << 3);
  }

  f32x4 acc[8][4];
#pragma unroll
  for (int i = 0; i < 8; ++i)
#pragma unroll
    for (int j = 0; j < 4; ++j) acc[i][j] = f32x4{0.f, 0.f, 0.f, 0.f};

  auto stage = [&](int buf, int kt) {
    const int k0 = kt << 6;
#pragma unroll
    for (int j = 0; j < 4; ++j)
      glds16(A + (size_t)(bm + srow[j]) * 1024 + k0 + skoff[j],
             &As[buf][((j << 9) + (w << 6)) << 3]);
#pragma unroll
    for (int j = 0; j < 4; ++j)
      glds16(Bt + (size_t)(bn + srow[j]) * 1024 + k0 + skoff[j],
             &Bs[buf][((j << 9) + (w << 6)) << 3]);
  };

  stage(0, 0);

  for (int kt = 0; kt < 16; ++kt) {
    const int cur = kt & 1;
    // my stage for tile kt was issued one iteration ago (a full tile-compute of slack)
    asm volatile("s_waitcnt vmcnt(0)" ::: "memory");
    __builtin_amdgcn_s_barrier();           // all waves' data visible; buf^1 readers quiesced
    __builtin_amdgcn_sched_barrier(0);      // nothing moves above the barrier
    if (kt < 15) stage(cur ^ 1, kt + 1);    // refill the other buffer (latency hides under compute)

#pragma unroll
    for (int qr = 0; qr < 2; ++qr) {
      short8 af[4][2];
#pragma unroll
      for (int ri = 0; ri < 4; ++ri)
#pragma unroll
        for (int ks = 0; ks < 2; ++ks) {
          int row = (wm << 7) + (qr << 6) + (ri << 4) + l15;
          int ch = ((ks << 2) + l4) ^ (row & 7);
          af[ri][ks] = *(const short8*)&As[cur][(row << 6) + (ch << 3)];
        }
#pragma unroll
      for (int qc = 0; qc < 2; ++qc) {
        short8 bfr[2][2];
#pragma unroll
        for (int ni = 0; ni < 2; ++ni)
#pragma unroll
          for (int ks = 0; ks < 2; ++ks) {
            int row = (wn << 6) + (qc << 5) + (ni << 4) + l15;
            int ch = ((ks << 2) + l4) ^ (row & 7);
            bfr[ni][ks] = *(const short8*)&Bs[cur][(row << 6) + (ch << 3)];
          }
        __builtin_amdgcn_s_setprio(1);
#pragma unroll
        for (int ks = 0; ks < 2; ++ks)
#pragma unroll
          for (int ri = 0; ri < 4; ++ri)
#pragma unroll
            for (int ni = 0; ni < 2; ++ni)
              acc[(qr << 2) + ri][(qc << 1) + ni] = __builtin_amdgcn_mfma_f32_16x16x32_bf16(
                  af[ri][ks], bfr[ni][ks], acc[(qr << 2) + ri][(qc << 1) + ni], 0, 0, 0);
        __builtin_amdgcn_s_setprio(0);
      }
    }
  }

  // epilogue: m = bm + wm*128 + mi*16 + l4*4 + r ; n = bn + wn*64 + ni*16 + l15
  if (MODE == 0) {
    const int nb = bn + (wn << 6);
    const int z = nb >> 10;  // wave-uniform (bn mult of 256, 256 | 1024)
    if (z < 2) {
      unsigned short* Oz = OutB + (size_t)z * 16777216;
#pragma unroll
      for (int mi = 0; mi < 8; ++mi) {
#pragma unroll
        for (int r = 0; r < 4; ++r) {
          int m = bm + (wm << 7) + (mi << 4) + (l4 << 2) + r;
          int b = m >> 10, t = m & 1023;
#pragma unroll
          for (int ni = 0; ni < 4; ++ni) {
            int n1 = (nb + (ni << 4) + l15) & 1023;
            int h = n1 >> 6, d = n1 & 63;
            Oz[((size_t)(b * 16 + h) * 1024 + t) * 64 + d] = f2bf(acc[mi][ni][r]);
          }
        }
      }
    } else {
      // V^T: [bh][d][t], pack 4 consecutive t per lane
      unsigned short* Oz = OutB + (size_t)2 * 16777216;
#pragma unroll
      for (int mi = 0; mi < 8; ++mi) {
        int tb = bm + (wm << 7) + (mi << 4) + (l4 << 2);
        int bb = tb >> 10, tt = tb & 1023;
#pragma unroll
        for (int ni = 0; ni < 4; ++ni) {
          int n1 = (nb + (ni << 4) + l15) & 1023;
          int hh = n1 >> 6, dd = n1 & 63;
          u16x4 pk;
#pragma unroll
          for (int r = 0; r < 4; ++r) pk[r] = f2bf(acc[mi][ni][r]);
          *(u16x4*)&Oz[(((size_t)((bb << 4) + hh) << 6) + (size_t)dd) * 1024 + tt] = pk;
        }
      }
    }
  } else {
#pragma unroll
    for (int mi = 0; mi < 8; ++mi) {
#pragma unroll
      for (int r = 0; r < 4; ++r) {
        int m = bm + (wm << 7) + (mi << 4) + (l4 << 2) + r;
#pragma unroll
        for (int ni = 0; ni < 4; ++ni) {
          int n = bn + (wn << 6) + (ni << 4) + l15;
          OutF[(size_t)m * 1024 + n] = acc[mi][ni][r] + bias[n];
        }
      }
    }
  }
}

// ---------------- causal flash attention (swapped QK^T, single-barrier dbuf) ----------------
// 1-D grid 2048, XCD swizzle: each XCD owns 32 consecutive bh (K/V L2-resident per XCD).
// block bx handles q-tiles {15-bx, bx} (17 KV-iters uniform). wave w owns 16 q rows.
// K [bh][t][64]; V^T [bh][d][t]; swapped S^T = mfma(K, Q) so softmax is lane-local.
__global__ __launch_bounds__(256)
void attn_fa(const unsigned short* __restrict__ Qb,
             const unsigned short* __restrict__ Kb,
             const unsigned short* __restrict__ Vtb,
             unsigned short* __restrict__ Ob) {
  __shared__ unsigned short Ks[2][64 * 64];  // [kv][k=64], chunk-swizzled
  __shared__ unsigned short Vs[2][64 * 64];  // V^T [d][kv=64], chunk-swizzled
  __shared__ unsigned short Ps[4][16 * 64];  // per-wave P [qrow][kv], chunk-swizzled
  const int tid = threadIdx.x, w = tid >> 6, lane = tid & 63;
  const int l15 = lane & 15, l4 = lane >> 4;
  const int phys = blockIdx.x;
  const int ord = phys >> 3;
  const int bx = ord & 7;
  const int bh = ((phys & 7) << 5) | (ord >> 3);
  const unsigned short* Q = Qb + ((size_t)bh << 16);
  const unsigned short* K = Kb + ((size_t)bh << 16);
  const unsigned short* Vt = Vtb + ((size_t)bh << 16);
  const int b = bh >> 4, h = bh & 15;
  const float SC = 0.125f * 1.44269504088896340736f;  // 1/sqrt(64) * log2(e)
  const float NEGINF = -__builtin_inff();

  int srow[2], skoff[2];
#pragma unroll
  for (int c = 0; c < 2; ++c) {
    int C = (c << 8) + tid;
    int row = C >> 3, cc = C & 7;
    srow[c] = row;
    skoff[c] = ((cc ^ (row & 7)) << 3);
  }
  const int sdst = (w << 6) << 3;

  for (int ph = 0; ph < 2; ++ph) {
    const int qidx = ph ? bx : (15 - bx);
    const int q0 = qidx << 6;
    const int nt = qidx + 1;
    const int qrow = q0 + (w << 4) + l15;

    short8 bq0, bq1;
    {
      const unsigned short* qp = Q + (size_t)qrow * 64 + (l4 << 3);
      bq0 = *(const short8*)qp;
      bq1 = *(const short8*)(qp + 32);
    }

    f32x4 o[4];
#pragma unroll
    for (int nf = 0; nf < 4; ++nf) o[nf] = f32x4{0.f, 0.f, 0.f, 0.f};
    float mreg = NEGINF, lreg = 0.f;

#pragma unroll
    for (int c = 0; c < 2; ++c) {
      glds16(K + (size_t)(srow[c] << 6) + skoff[c], &Ks[0][(c << 11) + sdst]);
      glds16(Vt + (size_t)(srow[c] << 10) + skoff[c], &Vs[0][(c << 11) + sdst]);
    }
    __syncthreads();

    for (int it = 0; it < nt; ++it) {
      const int cur = it & 1;
      if (it + 1 < nt) {
        const int kv0n = (it + 1) << 6;
#pragma unroll
        for (int c = 0; c < 2; ++c) {
          glds16(K + (size_t)((kv0n + srow[c]) << 6) + skoff[c], &Ks[cur ^ 1][(c << 11) + sdst]);
          glds16(Vt + (size_t)(srow[c] << 10) + kv0n + skoff[c], &Vs[cur ^ 1][(c << 11) + sdst]);
        }
      }

      f32x4 s[4];
      __builtin_amdgcn_s_setprio(1);
#pragma unroll
      for (int n = 0; n < 4; ++n) {
        const int row = (n << 4) + l15;
        const int rb = row << 6;
        short8 ak0 = *(const short8*)&Ks[cur][rb + ((l4 ^ (row & 7)) << 3)];
        short8 ak1 = *(const short8*)&Ks[cur][rb + (((4 + l4) ^ (row & 7)) << 3)];
        f32x4 a = f32x4{0.f, 0.f, 0.f, 0.f};
        a = __builtin_amdgcn_mfma_f32_16x16x32_bf16(ak0, bq0, a, 0, 0, 0);
        a = __builtin_amdgcn_mfma_f32_16x16x32_bf16(ak1, bq1, a, 0, 0, 0);
        s[n] = a;
      }
      __builtin_amdgcn_s_setprio(0);

      const int kv0 = it << 6;
      const bool diag = (it == nt - 1);
      float p[4][4];
      float mx = NEGINF;
#pragma unroll
      for (int n = 0; n < 4; ++n)
#pragma unroll
        for (int r = 0; r < 4; ++r) {
          float v = s[n][r] * SC;
          if (diag) {
            int kvg = kv0 + (n << 4) + (l4 << 2) + r;
            v = (kvg <= qrow) ? v : NEGINF;
          }
          p[n][r] = v;
          mx = fmaxf(mx, v);
        }
      mx = fmaxf(mx, __shfl_xor(mx, 16));
      mx = fmaxf(mx, __shfl_xor(mx, 32));
      float mnew = fmaxf(mreg, mx);
      float alpha = exp2f(mreg - mnew);
      mreg = mnew;
      float rs = 0.f;
#pragma unroll
      for (int n = 0; n < 4; ++n)
#pragma unroll
        for (int r = 0; r < 4; ++r) {
          float pv = exp2f(p[n][r] - mreg);
          p[n][r] = pv;
          rs += pv;
        }
      rs += __shfl_xor(rs, 16);
      rs += __shfl_xor(rs, 32);
      lreg = lreg * alpha + rs;

      float a_r[4];
#pragma unroll
      for (int r = 0; r < 4; ++r)
        a_r[r] = __shfl(alpha, (lane & 0x30) | ((l4 << 2) | r));
#pragma unroll
      for (int nf = 0; nf < 4; ++nf)
#pragma unroll
        for (int r = 0; r < 4; ++r) o[nf][r] *= a_r[r];

#pragma unroll
      for (int n = 0; n < 4; ++n) {
        u16x4 pk;
#pragma unroll
        for (int r = 0; r < 4; ++r) pk[r] = f2bf(p[n][r]);
        const int kc = (n << 1) + (l4 >> 1);
        char* addr = (char*)&Ps[w][0] + (l15 << 7) + ((kc ^ (l15 & 7)) << 4) + ((l4 & 1) << 3);
        *(u16x4*)addr = pk;
      }

      short8 pa0 = *(const short8*)((char*)&Ps[w][0] + (l15 << 7) + ((l4 ^ (l15 & 7)) << 4));
      short8 pa1 = *(const short8*)((char*)&Ps[w][0] + (l15 << 7) + (((4 + l4) ^ (l15 & 7)) << 4));
      __builtin_amdgcn_s_setprio(1);
#pragma unroll
      for (int nf = 0; nf < 4; ++nf) {
        const int drow = (nf << 4) + l15;
        const int db = drow << 6;
        short8 vb0 = *(const short8*)&Vs[cur][db + ((l4 ^ (drow & 7)) << 3)];
        short8 vb1 = *(const short8*)&Vs[cur][db + (((4 + l4) ^ (drow & 7)) << 3)];
        o[nf] = __builtin_amdgcn_mfma_f32_16x16x32_bf16(pa0, vb0, o[nf], 0, 0, 0);
        o[nf] = __builtin_amdgcn_mfma_f32_16x16x32_bf16(pa1, vb1, o[nf], 0, 0, 0);
      }
      __builtin_amdgcn_s_setprio(0);
      __syncthreads();
    }

    float linv = 1.0f / lreg;
    float l_r[4];
#pragma unroll
    for (int r = 0; r < 4; ++r)
      l_r[r] = __shfl(linv, (lane & 0x30) | ((l4 << 2) | r));
#pragma unroll
    for (int r = 0; r < 4; ++r) {
      const int t = q0 + (w << 4) + (l4 << 2) + r;
      size_t base = ((size_t)(b * 1024 + t) << 10) + (h << 6);
#pragma unroll
      for (int nf = 0; nf < 4; ++nf)
        Ob[base + (nf << 4) + l15] = f2bf(o[nf][r] * l_r[r]);
    }
  }
}

// ---------------- launch ----------------

extern "C" void kernel_launch(void* const* d_in, const int* in_sizes, int n_in,
                              void* d_out, int out_size, void* d_ws, size_t ws_size,
                              hipStream_t stream) {
  const float* x  = (const float*)d_in[0];
  const float* Wq = (const float*)d_in[1];
  const float* Wk = (const float*)d_in[2];
  const float* Wv = (const float*)d_in[3];
  const float* Wo = (const float*)d_in[4];
  const float* bo = (const float*)d_in[5];
  float* out = (float*)d_out;

  unsigned char* ws = (unsigned char*)d_ws;
  unsigned short* xb  = (unsigned short*)(ws);                          // 32 MB (aliased by O later)
  unsigned short* wT  = (unsigned short*)(ws + 33554432);               // 3 x 2 MB (WqT,WkT,WvT contiguous)
  unsigned short* woT = (unsigned short*)(ws + 33554432 + 6291456);     // 2 MB
  unsigned short* qkv = (unsigned short*)(ws + 41943040);               // q,k [bh][t][d]; v^T [bh][d][t]
  unsigned short* Ob  = xb;  // x bf16 is dead after projections

  cvt_x_kernel<<<2048, 256, 0, stream>>>(x, xb, 4194304);
  cvt_w3_kernel<<<12288, 256, 0, stream>>>(Wq, Wk, Wv, wT);
  cvt_w_kernel<<<4096, 256, 0, stream>>>(Wo, woT, 1 << 20, 10);

  gemm256<0><<<768, 512, 0, stream>>>(xb, wT, qkv, nullptr, nullptr);
  attn_fa<<<2048, 256, 0, stream>>>(qkv, qkv + 16777216, qkv + 33554432, Ob);
  gemm256<1><<<256, 512, 0, stream>>>(Ob, woT, nullptr, out, bo);
}